// Round 1
// baseline (417.100 us; speedup 1.0000x reference)
//
#include <hip/hip_runtime.h>

// Diffusion: x_{t+1}[n,c,i,j] = sum_{ki,kj} x_t[n,c,i+ki-1,j+kj-1] * |w_k|/sum|w|
// zero-padded borders; 8 steps; weight layout (n, c*9, h, w), k = ki*3+kj.

constexpr int H = 128, W = 128;
constexpr int PLANE = H * W;          // 16384
constexpr int TILE_H = 8;
constexpr int ROWS = TILE_H + 2;      // 10
constexpr int NPLANES = 4 * 64;       // 256
constexpr int TILES_PER_PLANE = H / TILE_H;  // 16

__global__ __launch_bounds__(256)
void diff_step(const float* __restrict__ x,
               const float* __restrict__ wgt,
               float* __restrict__ out)
{
    __shared__ float xs[ROWS * W];    // 5120 B; full-width tile -> halo cols are the zero pad

    const int tid   = threadIdx.x;
    const int plane = blockIdx.x >> 4;        // / TILES_PER_PLANE
    const int tile  = blockIdx.x & 15;
    const int i0    = tile * TILE_H;

    const float* xp = x + (size_t)plane * PLANE;
    // weight plane base: (n*576 + c*9) * PLANE == plane * 9 * PLANE
    const float* wb = wgt + (size_t)plane * 9 * PLANE;

    // --- stage x rows [i0-1 .. i0+8] into LDS (float4, coalesced) ---
    for (int idx = tid; idx < ROWS * (W / 4); idx += 256) {
        const int r  = idx >> 5;      // 0..9
        const int q  = idx & 31;      // float4 index in row
        const int gi = i0 - 1 + r;
        float4 v = make_float4(0.f, 0.f, 0.f, 0.f);
        if ((unsigned)gi < (unsigned)H)
            v = *reinterpret_cast<const float4*>(xp + gi * W + q * 4);
        *reinterpret_cast<float4*>(&xs[r * W + q * 4]) = v;
    }
    __syncthreads();

    const int r  = tid >> 5;          // 0..7  (output row within tile)
    const int jq = tid & 31;          // column quad
    const int j0 = jq * 4;
    const int i  = i0 + r;

    // x neighborhood: rows r..r+2 (LDS row r+di == global i-1+di), cols j0-1..j0+4
    float c[3][6];
    #pragma unroll
    for (int di = 0; di < 3; ++di) {
        float4 mid = *reinterpret_cast<const float4*>(&xs[(r + di) * W + j0]);
        float left  = __shfl_up(mid.w, 1);   // lane-1's col j0-1
        float right = __shfl_down(mid.x, 1); // lane+1's col j0+4
        if (jq == 0)  left  = 0.f;           // plane left border (zero pad)
        if (jq == 31) right = 0.f;           // plane right border
        c[di][0] = left;  c[di][1] = mid.x; c[di][2] = mid.y;
        c[di][3] = mid.z; c[di][4] = mid.w; c[di][5] = right;
    }

    // 9 coalesced float4 weight loads; inline |w| normalization
    float4 acc  = make_float4(0.f, 0.f, 0.f, 0.f);
    float4 wsum = make_float4(0.f, 0.f, 0.f, 0.f);
    const float* wrow = wb + i * W + j0;
    #pragma unroll
    for (int k = 0; k < 9; ++k) {
        float4 wv = *reinterpret_cast<const float4*>(wrow + (size_t)k * PLANE);
        const float a0 = fabsf(wv.x), a1 = fabsf(wv.y),
                    a2 = fabsf(wv.z), a3 = fabsf(wv.w);
        const int di = k / 3, dj = k % 3;
        acc.x  += a0 * c[di][dj + 0];
        acc.y  += a1 * c[di][dj + 1];
        acc.z  += a2 * c[di][dj + 2];
        acc.w  += a3 * c[di][dj + 3];
        wsum.x += a0; wsum.y += a1; wsum.z += a2; wsum.w += a3;
    }

    float4 o;
    o.x = acc.x / wsum.x;
    o.y = acc.y / wsum.y;
    o.z = acc.z / wsum.z;
    o.w = acc.w / wsum.w;
    *reinterpret_cast<float4*>(out + (size_t)plane * PLANE + i * W + j0) = o;
}

extern "C" void kernel_launch(void* const* d_in, const int* in_sizes, int n_in,
                              void* d_out, int out_size, void* d_ws, size_t ws_size,
                              hipStream_t stream)
{
    const float* x = (const float*)d_in[0];
    const float* w = (const float*)d_in[1];
    float* out = (float*)d_out;
    float* ws  = (float*)d_ws;     // needs 16 MiB ping-pong buffer

    const dim3 grid(NPLANES * TILES_PER_PLANE);   // 4096 blocks
    const dim3 block(256);

    // steps = min(max_step=8, max(h,w)=128) = 8 (static per harness inputs)
    // buffer chain: in -> ws -> out -> ws -> out -> ws -> out -> ws -> out
    diff_step<<<grid, block, 0, stream>>>(x, w, ws);           // step 1
    const float* src = ws;
    float*       dst = out;
    for (int s = 2; s <= 8; ++s) {
        diff_step<<<grid, block, 0, stream>>>(src, w, dst);
        float* t = dst;
        dst = (float*)src;
        src = t;
    }
}

// Round 2
// 379.192 us; speedup vs baseline: 1.1000x; 1.1000x over previous
//
#include <hip/hip_runtime.h>
#include <hip/hip_fp16.h>

// Fused 8-step diffusion: one block per (n,c) plane, all steps in one launch.
// x lives in registers (4 rows x 4 cols per thread), normalized |w| weights
// live in fp16 registers (loaded from HBM exactly once), row halos exchanged
// through 32KB static LDS, column halos via wave shuffles.

constexpr int H = 128, W = 128, PLANE = H * W;
constexpr int NSTEP = 8;

// build 6-wide column window from a float4 row segment (cols j0-1 .. j0+4)
#define MKWIN(D, V) do {                                                     \
    D[1] = (V).x; D[2] = (V).y; D[3] = (V).z; D[4] = (V).w;                  \
    float _l = __shfl_up((V).w, 1);                                          \
    float _r = __shfl_down((V).x, 1);                                        \
    D[0] = (quad == 0)  ? 0.f : _l;                                          \
    D[5] = (quad == 31) ? 0.f : _r;                                          \
} while (0)

// accumulate 9 taps for output row P from window rows R0,R1,R2 (di=0,1,2)
#define ACCP(P, R0, R1, R2, DST) do {                                        \
    float _a0 = 0.f, _a1 = 0.f, _a2 = 0.f, _a3 = 0.f;                        \
    const float* _rw[3] = { R0, R1, R2 };                                    \
    _Pragma("unroll")                                                        \
    for (int _di = 0; _di < 3; ++_di) {                                      \
        _Pragma("unroll")                                                    \
        for (int _dj = 0; _dj < 3; ++_dj) {                                  \
            const int _k = _di * 3 + _dj;                                    \
            _a0 = fmaf(__low2float (wh[P][_k][0]), _rw[_di][_dj + 0], _a0);  \
            _a1 = fmaf(__high2float(wh[P][_k][0]), _rw[_di][_dj + 1], _a1);  \
            _a2 = fmaf(__low2float (wh[P][_k][1]), _rw[_di][_dj + 2], _a2);  \
            _a3 = fmaf(__high2float(wh[P][_k][1]), _rw[_di][_dj + 3], _a3);  \
        }                                                                    \
    }                                                                        \
    DST = make_float4(_a0, _a1, _a2, _a3);                                   \
} while (0)

__global__ __launch_bounds__(1024, 4)
void diff_fused(const float* __restrict__ xin,
                const float* __restrict__ wgt,
                float* __restrict__ out)
{
    __shared__ float ldsT[32][W];   // row 4*rg   of current x, per row-group
    __shared__ float ldsB[32][W];   // row 4*rg+3 of current x, per row-group

    const int tid  = threadIdx.x;
    const int quad = tid & 31;      // column quad: cols 4q..4q+3
    const int rg   = tid >> 5;      // row-group: rows 4rg..4rg+3
    const int j0   = quad * 4;
    const int r0   = rg * 4;
    const size_t pbase = (size_t)blockIdx.x * PLANE;

    const float* __restrict__ xp = xin + pbase;
    const float* __restrict__ wb = wgt + pbase * 9;  // (n*576 + c*9)*PLANE

    // ---- x patch into registers (coalesced float4) ----
    float4 xr[4];
    #pragma unroll
    for (int p = 0; p < 4; ++p)
        xr[p] = *reinterpret_cast<const float4*>(xp + (r0 + p) * W + j0);

    // ---- weights: load once, |.|-normalize in fp32, hold as fp16 regs ----
    __half2 wh[4][9][2];   // [row p][tap k][col pair]
    #pragma unroll
    for (int p = 0; p < 4; ++p) {
        float a[9][4];
        float s0 = 0.f, s1 = 0.f, s2 = 0.f, s3 = 0.f;
        #pragma unroll
        for (int k = 0; k < 9; ++k) {
            float4 v = *reinterpret_cast<const float4*>(
                wb + (size_t)k * PLANE + (r0 + p) * W + j0);
            a[k][0] = fabsf(v.x); a[k][1] = fabsf(v.y);
            a[k][2] = fabsf(v.z); a[k][3] = fabsf(v.w);
            s0 += a[k][0]; s1 += a[k][1]; s2 += a[k][2]; s3 += a[k][3];
        }
        s0 = 1.f / s0; s1 = 1.f / s1; s2 = 1.f / s2; s3 = 1.f / s3;
        #pragma unroll
        for (int k = 0; k < 9; ++k) {
            wh[p][k][0] = __halves2half2(__float2half_rn(a[k][0] * s0),
                                         __float2half_rn(a[k][1] * s1));
            wh[p][k][1] = __halves2half2(__float2half_rn(a[k][2] * s2),
                                         __float2half_rn(a[k][3] * s3));
        }
    }

    // ---- 8 fused diffusion steps, zero global traffic ----
    for (int s = 0; s < NSTEP; ++s) {
        // publish boundary rows for vertical halo exchange
        *reinterpret_cast<float4*>(&ldsT[rg][j0]) = xr[0];
        *reinterpret_cast<float4*>(&ldsB[rg][j0]) = xr[3];
        __syncthreads();
        float4 up = make_float4(0.f, 0.f, 0.f, 0.f);  // global row r0-1
        float4 dn = make_float4(0.f, 0.f, 0.f, 0.f);  // global row r0+4
        if (rg > 0)  up = *reinterpret_cast<const float4*>(&ldsB[rg - 1][j0]);
        if (rg < 31) dn = *reinterpret_cast<const float4*>(&ldsT[rg + 1][j0]);
        __syncthreads();  // reads done; next step may overwrite LDS

        // rolling 6-col windows over input rows q=0..5 (r0-1 .. r0+4)
        float wa[6], wbw[6], wc[6];
        float4 t;
        MKWIN(wa,  up);       // q=0
        MKWIN(wbw, xr[0]);    // q=1
        MKWIN(wc,  xr[1]);    // q=2
        ACCP(0, wa, wbw, wc, t);
        xr[0] = t;                       // old xr[0] fully consumed
        MKWIN(wa,  xr[2]);    // q=3
        ACCP(1, wbw, wc, wa, t);
        xr[1] = t;
        MKWIN(wbw, xr[3]);    // q=4
        ACCP(2, wc, wa, wbw, t);
        xr[2] = t;
        MKWIN(wc,  dn);       // q=5
        ACCP(3, wa, wbw, wc, t);
        xr[3] = t;
    }

    // ---- store result (coalesced float4) ----
    float* __restrict__ op = out + pbase;
    #pragma unroll
    for (int p = 0; p < 4; ++p)
        *reinterpret_cast<float4*>(op + (r0 + p) * W + j0) = xr[p];
}

extern "C" void kernel_launch(void* const* d_in, const int* in_sizes, int n_in,
                              void* d_out, int out_size, void* d_ws, size_t ws_size,
                              hipStream_t stream)
{
    const float* x = (const float*)d_in[0];
    const float* w = (const float*)d_in[1];
    float* out = (float*)d_out;
    (void)d_ws; (void)ws_size; (void)in_sizes; (void)n_in; (void)out_size;

    // 256 planes (4 n x 64 c) -> 256 blocks -> one per CU
    diff_fused<<<dim3(4 * 64), dim3(1024), 0, stream>>>(x, w, out);
}